// Round 8
// baseline (221.593 us; speedup 1.0000x reference)
//
#include <hip/hip_runtime.h>

#define N_NODES 4096
#define N_EDGES 524288
#define HID 64

typedef short short8 __attribute__((ext_vector_type(8)));
typedef float f32x4 __attribute__((ext_vector_type(4)));
typedef float f32x16 __attribute__((ext_vector_type(16)));

__device__ __forceinline__ float bcastf(float v, int l) {
    return __int_as_float(__builtin_amdgcn_readlane(__float_as_int(v), l));
}

__device__ __forceinline__ void wave_sum2(float& a, float& b) {
    #pragma unroll
    for (int off = 32; off > 0; off >>= 1) {
        a += __shfl_xor(a, off, 64);
        b += __shfl_xor(b, off, 64);
    }
}

__device__ __forceinline__ short f2bf(float f) {         // RNE
    unsigned u = __float_as_uint(f);
    u = u + 0x7FFFu + ((u >> 16) & 1u);
    return (short)(u >> 16);
}
__device__ __forceinline__ float bf2f(short s) {
    return __uint_as_float(((unsigned)(unsigned short)s) << 16);
}
__device__ __forceinline__ void split_cheap(float f, short& hi, short& lo) {
    unsigned u = __float_as_uint(f);
    unsigned hb = u & 0xffff0000u;
    float lof = f - __uint_as_float(hb);
    hi = (short)(u >> 16);
    lo = (short)(__float_as_uint(lof) >> 16);
}

// pack 8 fp32 -> hi/lo bf16 planes via v_cvt_pk (RNE hi; lo = RNE(v - hi))
__device__ __forceinline__ void pack_plane8(const float* vv, short8& ah, short8& al) {
    union { unsigned u[4]; short8 s; } Uh, Ul;
    #pragma unroll
    for (int i = 0; i < 4; i++) {
        unsigned hw;
        asm("v_cvt_pk_bf16_f32 %0, %1, %2" : "=v"(hw) : "v"(vv[2 * i]), "v"(vv[2 * i + 1]));
        float he = __uint_as_float(hw << 16);
        float ho = __uint_as_float(hw & 0xffff0000u);
        float le = vv[2 * i] - he;
        float lo_ = vv[2 * i + 1] - ho;
        unsigned lw;
        asm("v_cvt_pk_bf16_f32 %0, %1, %2" : "=v"(lw) : "v"(le), "v"(lo_));
        Uh.u[i] = hw; Ul.u[i] = lw;
    }
    ah = Uh.s; al = Ul.s;
}

// pack 16 softmax probs (f32, regs) -> two bf16 B-fragments via cvt_pk + permlane32_swap
__device__ __forceinline__ void pack_pfrag(const float* p, short8& pf0s, short8& pf1s) {
    unsigned w0, w1, w2, w3, u0, u1, u2, u3;
    asm("v_cvt_pk_bf16_f32 %0, %1, %2" : "=v"(w0) : "v"(p[0]), "v"(p[1]));
    asm("v_cvt_pk_bf16_f32 %0, %1, %2" : "=v"(w1) : "v"(p[2]), "v"(p[3]));
    asm("v_cvt_pk_bf16_f32 %0, %1, %2" : "=v"(w2) : "v"(p[4]), "v"(p[5]));
    asm("v_cvt_pk_bf16_f32 %0, %1, %2" : "=v"(w3) : "v"(p[6]), "v"(p[7]));
    asm("v_cvt_pk_bf16_f32 %0, %1, %2" : "=v"(u0) : "v"(p[8]), "v"(p[9]));
    asm("v_cvt_pk_bf16_f32 %0, %1, %2" : "=v"(u1) : "v"(p[10]), "v"(p[11]));
    asm("v_cvt_pk_bf16_f32 %0, %1, %2" : "=v"(u2) : "v"(p[12]), "v"(p[13]));
    asm("v_cvt_pk_bf16_f32 %0, %1, %2" : "=v"(u3) : "v"(p[14]), "v"(p[15]));
    asm("v_permlane32_swap_b32 %0, %1" : "+v"(w0), "+v"(w2));
    asm("v_permlane32_swap_b32 %0, %1" : "+v"(w1), "+v"(w3));
    asm("v_permlane32_swap_b32 %0, %1" : "+v"(u0), "+v"(u2));
    asm("v_permlane32_swap_b32 %0, %1" : "+v"(u1), "+v"(u3));
    union { unsigned u[4]; short8 s; } pf0, pf1;
    pf0.u[0] = w0; pf0.u[1] = w1; pf0.u[2] = w2; pf0.u[3] = w3;
    pf1.u[0] = u0; pf1.u[1] = u1; pf1.u[2] = u2; pf1.u[3] = u3;
    pf0s = pf0.s; pf1s = pf1.s;
}

// --- fused prep: dst histogram+rank, A1 = W1[:, :14] @ xe + b1 (fp32 exact),
//     W2' = W2 * ln_g (cols) prepack hi/lo, b2' = b2 + W2 @ ln_b, w14 pack, ip prepack ---
__global__ void hist_prep(const float* __restrict__ x, const float* __restrict__ emb,
                          const int* __restrict__ etype, const int* __restrict__ ei,
                          const float* __restrict__ w1, const float* __restrict__ b1,
                          const float* __restrict__ w2, const float* __restrict__ lng,
                          const float* __restrict__ lnb, const float* __restrict__ b2,
                          const float* __restrict__ ipw,
                          float* __restrict__ A1, int* __restrict__ cnt, int* __restrict__ rank,
                          unsigned short* __restrict__ w2fh, unsigned short* __restrict__ w2fl,
                          unsigned short* __restrict__ ipfh, unsigned short* __restrict__ ipfl,
                          float* __restrict__ b2p, float* __restrict__ w14p) {
    int tid = blockIdx.x * 256 + threadIdx.x;    // grid exactly E
    int d = ei[N_EDGES + tid];
    rank[tid] = atomicAdd(&cnt[d], 1);
    if (tid < N_NODES * 64) {
        int n = tid >> 6, f = tid & 63;
        const float* wr = w1 + f * 15;
        float acc = b1[f];
        #pragma unroll
        for (int k = 0; k < 6; k++) acc = fmaf(x[n * 6 + k], wr[k], acc);
        int e = etype[n];
        #pragma unroll
        for (int k = 0; k < 8; k++) acc = fmaf(emb[e * 8 + k], wr[6 + k], acc);
        A1[tid] = acc;
    }
    if (tid < 4096) {
        int idx = tid >> 9, ln = (tid >> 3) & 63, j = tid & 7;
        int mm = ln & 15, qq = ln >> 4;
        int g = idx >> 1, tt = idx & 1;
        int col = tt * 32 + qq * 8 + j;
        float w = w2[(g * 16 + mm) * 64 + col] * lng[col];
        short hi = f2bf(w);
        w2fh[tid] = (unsigned short)hi;
        w2fl[tid] = (unsigned short)f2bf(w - bf2f(hi));
    }
    if (tid < 12288) {
        int idx = tid >> 9, ln = (tid >> 3) & 63, j = tid & 7;
        int mm = ln & 15, qq = ln >> 4;
        int og = idx >> 1, tt = idx & 1;
        float w = ipw[(og * 16 + mm) * 64 + tt * 32 + qq * 8 + j];
        short hi = f2bf(w);
        ipfh[tid] = (unsigned short)hi;
        ipfl[tid] = (unsigned short)f2bf(w - bf2f(hi));
    }
    if (tid < 64) {
        float acc = b2[tid];
        for (int c = 0; c < 64; c++) acc = fmaf(w2[tid * 64 + c], lnb[c], acc);
        b2p[tid] = acc;
        w14p[tid] = w1[tid * 15 + 14];
    }
}

// ------- scatter with in-block scan (int4 cnt loads) -------
__global__ void __launch_bounds__(256) scatter_scan(
        const int* __restrict__ cnt, const int* __restrict__ ei,
        const float* __restrict__ edge_attr, const int* __restrict__ rank,
        int* __restrict__ bnd,
        int* __restrict__ ssrc, float* __restrict__ sea) {
    __shared__ int lbnd[4096];
    __shared__ int wsum[4];
    int t = threadIdx.x;
    int base = t * 16;
    int v16[16];
    int T = 0;
    #pragma unroll
    for (int j4 = 0; j4 < 4; j4++) {
        int4 c4 = ((const int4*)cnt)[t * 4 + j4];
        v16[j4 * 4 + 0] = c4.x; v16[j4 * 4 + 1] = c4.y;
        v16[j4 * 4 + 2] = c4.z; v16[j4 * 4 + 3] = c4.w;
        T += c4.x + c4.y + c4.z + c4.w;
    }
    int inc = T;
    int l = t & 63;
    #pragma unroll
    for (int off = 1; off < 64; off <<= 1) {
        int v = __shfl_up(inc, off, 64);
        if (l >= off) inc += v;
    }
    if (l == 63) wsum[t >> 6] = inc;
    __syncthreads();
    int wo = 0;
    for (int w = 0; w < (t >> 6); w++) wo += wsum[w];
    int run = wo + inc - T;
    #pragma unroll
    for (int j = 0; j < 16; j++) {
        lbnd[base + j] = run;
        run += v16[j];
    }
    if (blockIdx.x == 0) {
        #pragma unroll
        for (int j = 0; j < 16; j++) bnd[base + j] = lbnd[base + j];
        if (t == 255) bnd[4096] = run;
    }
    __syncthreads();
    int e = blockIdx.x * 256 + t;
    int d = ei[N_EDGES + e];
    int pos = lbnd[d] + rank[e];
    ssrc[pos] = ei[e];
    sea[pos] = edge_attr[e];
}

// ---------------- edge MLP v5: swapped layer-2 MFMA + 2-deep decoupled prefetch (unchanged) ---
__global__ void __launch_bounds__(256, 3) edge_gather_mfma(
        const float* __restrict__ A1,
        const int* __restrict__ ssrc, const float* __restrict__ sea,
        const int* __restrict__ bnd,
        const unsigned short* __restrict__ w2fh, const unsigned short* __restrict__ w2fl,
        const float* __restrict__ w14p, const float* __restrict__ b2p,
        const float* __restrict__ lg, const float* __restrict__ lb,
        float* __restrict__ h) {
    __shared__ uint4 lw2h4[512];
    __shared__ uint4 lw2l4[512];
    int tid = threadIdx.x;
    {   // stage W2' hi/lo fragments (8 KB each) into LDS
        const uint4* gh = (const uint4*)w2fh;
        const uint4* gl = (const uint4*)w2fl;
        lw2h4[tid] = gh[tid];
        lw2h4[tid + 256] = gh[tid + 256];
        lw2l4[tid] = gl[tid];
        lw2l4[tid + 256] = gl[tid + 256];
    }
    const unsigned short* lw2h = (const unsigned short*)lw2h4;
    const unsigned short* lw2l = (const unsigned short*)lw2l4;

    int lane = tid & 63;
    int wv = tid >> 6;
    int m = lane & 15;
    int q = lane >> 4;

    float w14f[16];
    {
        float4 wa = *(const float4*)(w14p + q * 8);
        float4 wb = *(const float4*)(w14p + q * 8 + 4);
        float4 wc = *(const float4*)(w14p + 32 + q * 8);
        float4 wd = *(const float4*)(w14p + 32 + q * 8 + 4);
        w14f[0] = wa.x; w14f[1] = wa.y; w14f[2] = wa.z; w14f[3] = wa.w;
        w14f[4] = wb.x; w14f[5] = wb.y; w14f[6] = wb.z; w14f[7] = wb.w;
        w14f[8] = wc.x; w14f[9] = wc.y; w14f[10] = wc.z; w14f[11] = wc.w;
        w14f[12] = wd.x; w14f[13] = wd.y; w14f[14] = wd.z; w14f[15] = wd.w;
    }
    float b2v[16];
    #pragma unroll
    for (int g = 0; g < 4; g++) {
        float4 bb = *(const float4*)(b2p + g * 16 + q * 4);
        b2v[g * 4 + 0] = bb.x; b2v[g * 4 + 1] = bb.y;
        b2v[g * 4 + 2] = bb.z; b2v[g * 4 + 3] = bb.w;
    }
    __syncthreads();

    int node = blockIdx.x * 4 + wv;
    int start = bnd[node], end = bnd[node + 1];
    int ntiles = (end - start + 15) >> 4;
    float acc[16];
    #pragma unroll
    for (int i = 0; i < 16; i++) acc[i] = 0.f;

    if (ntiles > 0) {
        int ec0 = start + m; if (ec0 >= end) ec0 = end - 1;
        int srcn0 = ssrc[ec0]; float eav0 = sea[ec0];
        int srcn1 = srcn0; float eav1 = eav0;
        if (ntiles > 1) {
            int ec1 = start + 16 + m; if (ec1 >= end) ec1 = end - 1;
            srcn1 = ssrc[ec1]; eav1 = sea[ec1];
        }
        const float* ar = A1 + srcn0 * 64 + q * 8;
        float4 va = *(const float4*)(ar);
        float4 vb = *(const float4*)(ar + 4);
        float4 vc = *(const float4*)(ar + 32);
        float4 vd = *(const float4*)(ar + 36);

        for (int t = 0; t < ntiles; t++) {
            int base = start + t * 16;
            const float* arn = A1 + srcn1 * 64 + q * 8;
            float4 na = *(const float4*)(arn);
            float4 nb = *(const float4*)(arn + 4);
            float4 nc = *(const float4*)(arn + 32);
            float4 nd = *(const float4*)(arn + 36);
            int srcn2 = srcn1; float eav2 = eav1;
            if (t + 2 < ntiles) {
                int ec2 = base + 32 + m; if (ec2 >= end) ec2 = end - 1;
                srcn2 = ssrc[ec2]; eav2 = sea[ec2];
            }
            float v[16] = {va.x, va.y, va.z, va.w, vb.x, vb.y, vb.z, vb.w,
                           vc.x, vc.y, vc.z, vc.w, vd.x, vd.y, vd.z, vd.w};
            float eavc = eav0;
            float s = 0.f, s2 = 0.f;
            #pragma unroll
            for (int j = 0; j < 16; j++) {
                float u = fmaxf(fmaf(w14f[j], eavc, v[j]), 0.f);
                v[j] = u;
                s += u;
                s2 = fmaf(u, u, s2);
            }
            s += __shfl_xor(s, 16, 64);  s2 += __shfl_xor(s2, 16, 64);
            s += __shfl_xor(s, 32, 64);  s2 += __shfl_xor(s2, 32, 64);
            float mean = s * (1.f / 64.f);
            float var = s2 * (1.f / 64.f) - mean * mean;
            float rs = rsqrtf(var + 1e-5f);
            float a0 = -mean * rs;
            #pragma unroll
            for (int j = 0; j < 16; j++) v[j] = fmaf(v[j], rs, a0);
            short8 a2h[2], a2l[2];
            pack_plane8(v, a2h[0], a2l[0]);
            pack_plane8(v + 8, a2h[1], a2l[1]);
            int ob = (t >> 20);
            float s_ = 0.f, s2_ = 0.f;
            float t2v[16];
            #pragma unroll
            for (int g = 0; g < 4; g++) {
                f32x4 c = {0.f, 0.f, 0.f, 0.f};
                #pragma unroll
                for (int t2 = 0; t2 < 2; t2++) {
                    short8 bh = *(const short8*)(lw2h + ((g * 2 + t2) * 64 + lane + ob) * 8);
                    short8 bl = *(const short8*)(lw2l + ((g * 2 + t2) * 64 + lane + ob) * 8);
                    c = __builtin_amdgcn_mfma_f32_16x16x32_bf16(bh, a2l[t2], c, 0, 0, 0);
                    c = __builtin_amdgcn_mfma_f32_16x16x32_bf16(bl, a2h[t2], c, 0, 0, 0);
                    c = __builtin_amdgcn_mfma_f32_16x16x32_bf16(bh, a2h[t2], c, 0, 0, 0);
                }
                #pragma unroll
                for (int r = 0; r < 4; r++) {
                    float vv = fmaxf(c[r] + b2v[g * 4 + r], 0.f);
                    t2v[g * 4 + r] = vv;
                    s_ += vv;
                    s2_ = fmaf(vv, vv, s2_);
                }
            }
            s_ += __shfl_xor(s_, 16, 64);  s2_ += __shfl_xor(s2_, 16, 64);
            s_ += __shfl_xor(s_, 32, 64);  s2_ += __shfl_xor(s2_, 32, 64);
            float mean2 = s_ * (1.f / 64.f);
            float var2 = s2_ * (1.f / 64.f) - mean2 * mean2;
            float rs2 = rsqrtf(var2 + 1e-5f);
            float a02 = -mean2 * rs2;
            if (base + m < end) {
                #pragma unroll
                for (int i = 0; i < 16; i++) acc[i] += fmaf(t2v[i], rs2, a02);
            }
            va = na; vb = nb; vc = nc; vd = nd;
            eav0 = eav1; eav1 = eav2; srcn1 = srcn2;
        }
    }
    #pragma unroll
    for (int off = 1; off < 16; off <<= 1)
        #pragma unroll
        for (int i = 0; i < 16; i++) acc[i] += __shfl_xor(acc[i], off, 64);
    if (m == 0) {
        float deg = (float)(end - start);
        #pragma unroll
        for (int g = 0; g < 4; g++) {
            float4 lgv = *(const float4*)(lg + g * 16 + q * 4);
            float4 lbv = *(const float4*)(lb + g * 16 + q * 4);
            float* hp = h + node * 64 + g * 16 + q * 4;
            hp[0] = lgv.x * acc[g * 4 + 0] + deg * lbv.x;
            hp[1] = lgv.y * acc[g * 4 + 1] + deg * lbv.y;
            hp[2] = lgv.z * acc[g * 4 + 2] + deg * lbv.z;
            hp[3] = lgv.w * acc[g * 4 + 3] + deg * lbv.w;
        }
    }
}

// ------- qkv via MFMA: 3072 wave-tasks, 768 blocks (unchanged) -------
__global__ void __launch_bounds__(256) qkv_mfma(
        const float* __restrict__ h, const float* __restrict__ b,
        const unsigned short* __restrict__ ipfh, const unsigned short* __restrict__ ipfl,
        unsigned short* __restrict__ qhp, unsigned short* __restrict__ qlp,
        unsigned short* __restrict__ khp, unsigned short* __restrict__ klp,
        unsigned short* __restrict__ vT) {
    int lane = threadIdx.x & 63;
    int wv = threadIdx.x >> 6;
    int m = lane & 15;
    int q = lane >> 4;
    int wid = blockIdx.x * 4 + wv;   // 0..3071
    int tile = wid / 12;
    int og = wid - tile * 12;
    short8 bh[2], bl[2];
    #pragma unroll
    for (int t = 0; t < 2; t++) {
        bh[t] = *(const short8*)(ipfh + ((og * 2 + t) * 64 + lane) * 8);
        bl[t] = *(const short8*)(ipfl + ((og * 2 + t) * 64 + lane) * 8);
    }
    f32x4 c = {0.f, 0.f, 0.f, 0.f};
    #pragma unroll
    for (int t = 0; t < 2; t++) {
        const float* hr = h + (tile * 16 + m) * 64 + t * 32 + q * 8;
        float4 f0 = *(const float4*)hr;
        float4 f1 = *(const float4*)(hr + 4);
        float av8[8] = {f0.x, f0.y, f0.z, f0.w, f1.x, f1.y, f1.z, f1.w};
        short8 ah, al;
        #pragma unroll
        for (int j = 0; j < 8; j++) {
            short hi, lo;
            split_cheap(av8[j], hi, lo);
            ah[j] = hi;
            al[j] = lo;
        }
        c = __builtin_amdgcn_mfma_f32_16x16x32_bf16(al, bh[t], c, 0, 0, 0);
        c = __builtin_amdgcn_mfma_f32_16x16x32_bf16(ah, bl[t], c, 0, 0, 0);
        c = __builtin_amdgcn_mfma_f32_16x16x32_bf16(ah, bh[t], c, 0, 0, 0);
    }
    int o = og * 16 + m;
    float bias = b[o];
    #pragma unroll
    for (int r = 0; r < 4; r++) {
        int node = tile * 16 + q * 4 + r;   // C-layout row = (lane>>4)*4 + reg
        float val = c[r] + bias;
        if (og < 4) {
            float aq = val * (0.25f * 1.44269504f);   // fold 1/sqrt(16)*log2(e)
            size_t idx = ((size_t)(og * N_NODES + node)) * 16 + m;
            short hi = f2bf(aq);
            qhp[idx] = (unsigned short)hi;
            qlp[idx] = (unsigned short)f2bf(aq - bf2f(hi));
        } else if (og < 8) {
            size_t idx = ((size_t)((og - 4) * N_NODES + node)) * 16 + m;
            short hi = f2bf(val);
            khp[idx] = (unsigned short)hi;
            klp[idx] = (unsigned short)f2bf(val - bf2f(hi));
        } else {
            int feat = (og - 8) * 16 + m;
            vT[(size_t)feat * N_NODES + node] = (unsigned short)f2bf(val);
        }
    }
}

// ------- attention v3: 64-key iterations, dual independent S-tiles (ILP),
//         tree max, one rescale/branch per 64 keys, single Ot accumulator ----------
__global__ void __launch_bounds__(256) attn_mfma(
        const unsigned short* __restrict__ qhp, const unsigned short* __restrict__ qlp,
        const unsigned short* __restrict__ khp, const unsigned short* __restrict__ klp,
        const unsigned short* __restrict__ vT,
        float* __restrict__ part_o, float* __restrict__ part_ml) {
    int lane = threadIdx.x & 63;
    int wv = threadIdx.x >> 6;
    int l31 = lane & 31;
    int hi = lane >> 5;
    const short8 vones = {0x3F80, 0x3F80, 0x3F80, 0x3F80, 0x3F80, 0x3F80, 0x3F80, 0x3F80};

    int wid = blockIdx.x * 4 + wv;     // 0..4095
    int kc = wid & 7;                  // 8 chunks of 512 keys
    int wqt = (wid >> 3) & 127;        // 128 tiles of 32 q-rows
    int head = wid >> 10;

    int qrow = wqt * 32 + l31;
    short8 aqh = *(const short8*)(qhp + ((size_t)(head * N_NODES + qrow)) * 16 + hi * 8);
    short8 aql = *(const short8*)(qlp + ((size_t)(head * N_NODES + qrow)) * 16 + hi * 8);

    const unsigned short* khb = khp + (size_t)head * N_NODES * 16;
    const unsigned short* klb = klp + (size_t)head * N_NODES * 16;
    const unsigned short* vtb = vT + (size_t)(head * 16 + (l31 & 15)) * N_NODES;

    float mS = -3e38f;
    f32x16 Ot = {0.f, 0.f, 0.f, 0.f, 0.f, 0.f, 0.f, 0.f,
                 0.f, 0.f, 0.f, 0.f, 0.f, 0.f, 0.f, 0.f};

    for (int it = 0; it < 8; it++) {
        int n0 = kc * 512 + it * 64;
        // two independent 32-key sub-tiles: loads + 6 interleavable MFMAs
        size_t ka = ((size_t)(n0 + l31)) * 16 + hi * 8;
        size_t kb = ka + 32 * 16;
        short8 kah = *(const short8*)(khb + ka);
        short8 kal = *(const short8*)(klb + ka);
        short8 kbh = *(const short8*)(khb + kb);
        short8 kbl = *(const short8*)(klb + kb);
        f32x16 SA = {0.f, 0.f, 0.f, 0.f, 0.f, 0.f, 0.f, 0.f,
                     0.f, 0.f, 0.f, 0.f, 0.f, 0.f, 0.f, 0.f};
        f32x16 SB = SA;
        SA = __builtin_amdgcn_mfma_f32_32x32x16_bf16(kah, aql, SA, 0, 0, 0);
        SB = __builtin_amdgcn_mfma_f32_32x32x16_bf16(kbh, aql, SB, 0, 0, 0);
        SA = __builtin_amdgcn_mfma_f32_32x32x16_bf16(kal, aqh, SA, 0, 0, 0);
        SB = __builtin_amdgcn_mfma_f32_32x32x16_bf16(kbl, aqh, SB, 0, 0, 0);
        SA = __builtin_amdgcn_mfma_f32_32x32x16_bf16(kah, aqh, SA, 0, 0, 0);
        SB = __builtin_amdgcn_mfma_f32_32x32x16_bf16(kbh, aqh, SB, 0, 0, 0);
        // per-q max over 64 keys: depth-5 tree + partner-half swap
        float t0[8];
        #pragma unroll
        for (int r = 0; r < 8; r++)
            t0[r] = fmaxf(fmaxf(SA[r], SA[r + 8]), fmaxf(SB[r], SB[r + 8]));
        t0[0] = fmaxf(t0[0], t0[4]); t0[1] = fmaxf(t0[1], t0[5]);
        t0[2] = fmaxf(t0[2], t0[6]); t0[3] = fmaxf(t0[3], t0[7]);
        t0[0] = fmaxf(t0[0], t0[2]); t0[1] = fmaxf(t0[1], t0[3]);
        float mr = fmaxf(t0[0], t0[1]);
        mr = fmaxf(mr, __shfl_xor(mr, 32, 64));
        if (!__all(mr <= mS)) {          // exact skip: alpha == 1 when no new max
            float mn = fmaxf(mS, mr);
            float alpha = exp2f(mS - mn);
            mS = mn;
            #pragma unroll
            for (int r = 0; r < 9; r++) Ot[r] *= alpha;   // regs 0..7 = O, reg 8 = l
        }
        // softmax in place (S dead after), both tiles
        #pragma unroll
        for (int r = 0; r < 16; r++) SA[r] = exp2f(SA[r] - mS);
        #pragma unroll
        for (int r = 0; r < 16; r++) SB[r] = exp2f(SB[r] - mS);
        // sub-tile A: pack + PV
        {
            float p[16];
            #pragma unroll
            for (int r = 0; r < 16; r++) p[r] = SA[r];
            short8 pf0, pf1;
            pack_pfrag(p, pf0, pf1);
            short8 v0, v1;
            if (l31 < 16) {
                v0 = *(const short8*)(vtb + n0 + hi * 8);
                v1 = *(const short8*)(vtb + n0 + 16 + hi * 8);
            } else if (l31 == 16) {
                v0 = vones; v1 = vones;
            } else {
                v0 = (short8)0; v1 = (short8)0;
            }
            Ot = __builtin_amdgcn_mfma_f32_32x32x16_bf16(v0, pf0, Ot, 0, 0, 0);
            Ot = __builtin_amdgcn_mfma_f32_32x32x16_bf16(v1, pf1, Ot, 0, 0, 0);
        }
        // sub-tile B: pack + PV
        {
            float p[16];
            #pragma unroll
            for (int r = 0; r < 16; r++) p[r] = SB[r];
            short8 pf0, pf1;
            pack_pfrag(p, pf0, pf1);
            short8 v0, v1;
            if (l31 < 16) {
                v0 = *(const short8*)(vtb + n0 + 32 + hi * 8);
                v1 = *(const short8*)(vtb + n0 + 48 + hi * 8);
            } else if (l31 == 16) {
                v0 = vones; v1 = vones;
            } else {
                v0 = (short8)0; v1 = (short8)0;
            }
            Ot = __builtin_amdgcn_mfma_f32_32x32x16_bf16(v0, pf0, Ot, 0, 0, 0);
            Ot = __builtin_amdgcn_mfma_f32_32x32x16_bf16(v1, pf1, Ot, 0, 0, 0);
        }
    }
    int qt16 = wqt * 2 + (l31 >> 4);
    int qi = l31 & 15;
    size_t pb = ((size_t)(head * 8 + kc) * 256 + qt16) * 256;
    f32x4 o0 = {Ot[0], Ot[1], Ot[2], Ot[3]};
    f32x4 o1 = {Ot[4], Ot[5], Ot[6], Ot[7]};
    *(f32x4*)(part_o + pb + qi * 16 + hi * 4) = o0;
    *(f32x4*)(part_o + pb + qi * 16 + 8 + hi * 4) = o1;
    if (lane < 32) {
        size_t mb = ((size_t)(head * 8 + kc) * 256 + qt16) * 32;
        part_ml[mb + qi] = mS;
        part_ml[mb + 16 + qi] = Ot[8];
    }
}

// ---------------- fused merge (8 chunks) + out_proj + residual + LN + final (unchanged) ------
__global__ void post_kernel(const float* __restrict__ h,
                            const float* __restrict__ part_o, const float* __restrict__ part_ml,
                            const float* __restrict__ opw, const float* __restrict__ opb,
                            const float* __restrict__ ag, const float* __restrict__ ab,
                            const float* __restrict__ ow, const float* __restrict__ ob,
                            float* __restrict__ out) {
    __shared__ float wl1[64 * 65];
    __shared__ float wl2[64 * 65];
    for (int i = threadIdx.x; i < 4096; i += blockDim.x) {
        int r = i >> 6, c = i & 63;
        wl1[r * 65 + c] = opw[i];
        wl2[r * 65 + c] = ow[i];
    }
    __syncthreads();
    int lane = threadIdx.x & 63;
    int n = blockIdx.x * 4 + (threadIdx.x >> 6);
    int j = lane;
    int head = j >> 4, d = j & 15;
    int qt = n >> 4, qi = n & 15;
    float M = -3e38f, L = 0.f, Ov = 0.f;
    #pragma unroll
    for (int c = 0; c < 8; c++) {
        size_t base = ((size_t)(head * 8 + c) * 256 + qt);
        float mc = part_ml[base * 32 + qi];
        float lc = part_ml[base * 32 + 16 + qi];
        float ov = part_o[base * 256 + qi * 16 + d];
        if (mc > M) {
            float sc = exp2f(M - mc);
            M = mc;
            L = L * sc + lc;
            Ov = Ov * sc + ov;
        } else {
            float sc = exp2f(mc - M);
            L = fmaf(lc, sc, L);
            Ov = fmaf(ov, sc, Ov);
        }
    }
    float oj = Ov / L;
    float acc = opb[j];
    #pragma unroll
    for (int k = 0; k < 64; k++) acc = fmaf(wl1[j * 65 + k], bcastf(oj, k), acc);
    float r = h[n * 64 + j] + acc;
    float s = r, s2 = r * r;
    wave_sum2(s, s2);
    float mean = s * (1.f / 64.f);
    float var = s2 * (1.f / 64.f) - mean * mean;
    float hn = (r - mean) * rsqrtf(var + 1e-5f) * ag[j] + ab[j];
    float acc2 = ob[j];
    #pragma unroll
    for (int k = 0; k < 64; k++) acc2 = fmaf(wl2[j * 65 + k], bcastf(hn, k), acc2);
    out[n * 64 + j] = acc2;
}

extern "C" void kernel_launch(void* const* d_in, const int* in_sizes, int n_in,
                              void* d_out, int out_size, void* d_ws, size_t ws_size,
                              hipStream_t stream) {
    const float* x        = (const float*)d_in[0];
    const float* edge_attr= (const float*)d_in[1];
    const float* emb      = (const float*)d_in[2];
    const float* lin1_w   = (const float*)d_in[3];
    const float* lin1_b   = (const float*)d_in[4];
    const float* lay_w    = (const float*)d_in[5];
    const float* lay_b    = (const float*)d_in[6];
    const float* ln_g     = (const float*)d_in[7];
    const float* ln_b     = (const float*)d_in[8];
    const float* ipw      = (const float*)d_in[9];
    const float* ipb      = (const float*)d_in[10];
    const float* opw      = (const float*)d_in[11];
    const float* opb      = (const float*)d_in[12];
    const float* ang      = (const float*)d_in[13];
    const float* anb      = (const float*)d_in[14];
    const float* ow       = (const float*)d_in[15];
    const float* ob       = (const float*)d_in[16];
    const int*   ei       = (const int*)d_in[17];
    const int*   et       = (const int*)d_in[18];

    char* wsb = (char*)d_ws;
    size_t off = 0;
    float* A1             = (float*)(wsb + off);          off += 1048576;
    float* h              = (float*)(wsb + off);          off += 1048576;
    unsigned short* qhp   = (unsigned short*)(wsb + off); off += 524288;
    unsigned short* qlp   = (unsigned short*)(wsb + off); off += 524288;
    unsigned short* khp   = (unsigned short*)(wsb + off); off += 524288;
    unsigned short* klp   = (unsigned short*)(wsb + off); off += 524288;
    unsigned short* vT    = (unsigned short*)(wsb + off); off += 524288;
    float* part_o         = (float*)(wsb + off);          off += 8388608;
    float* part_ml        = (float*)(wsb + off);          off += 1048576;
    int*   cnt            = (int*)(wsb + off);            off += 16384;
    int*   bnd            = (int*)(wsb + off);            off += 16388;
    off = (off + 255) & ~(size_t)255;
    int*   rank           = (int*)(wsb + off);            off += 2097152;
    int*   ssrc           = (int*)(wsb + off);            off += 2097152;
    float* sea            = (float*)(wsb + off);          off += 2097152;
    unsigned short* w2fh  = (unsigned short*)(wsb + off); off += 8192;
    unsigned short* w2fl  = (unsigned short*)(wsb + off); off += 8192;
    unsigned short* ipfh  = (unsigned short*)(wsb + off); off += 24576;
    unsigned short* ipfl  = (unsigned short*)(wsb + off); off += 24576;
    float* b2p            = (float*)(wsb + off);          off += 256;
    float* w14p           = (float*)(wsb + off);          off += 256;

    (void)hipMemsetAsync(cnt, 0, 4096 * sizeof(int), stream);
    hist_prep<<<2048, 256, 0, stream>>>(x, emb, et, ei, lin1_w, lin1_b, lay_w, ln_g, ln_b,
                                        lay_b, ipw, A1, cnt, rank, w2fh, w2fl, ipfh, ipfl,
                                        b2p, w14p);
    scatter_scan<<<2048, 256, 0, stream>>>(cnt, ei, edge_attr, rank, bnd, ssrc, sea);
    edge_gather_mfma<<<1024, 256, 0, stream>>>(A1, ssrc, sea, bnd, w2fh, w2fl,
                                               w14p, b2p, ln_g, ln_b, h);
    qkv_mfma<<<768, 256, 0, stream>>>(h, ipb, ipfh, ipfl, qhp, qlp, khp, klp, vT);
    attn_mfma<<<1024, 256, 0, stream>>>(qhp, qlp, khp, klp, vT, part_o, part_ml);
    post_kernel<<<1024, 256, 0, stream>>>(h, part_o, part_ml, opw, opb, ang, anb, ow, ob,
                                          (float*)d_out);
}

// Round 9
// 219.136 us; speedup vs baseline: 1.0112x; 1.0112x over previous
//
#include <hip/hip_runtime.h>

#define N_NODES 4096
#define N_EDGES 524288
#define HID 64

typedef short short8 __attribute__((ext_vector_type(8)));
typedef float f32x4 __attribute__((ext_vector_type(4)));
typedef float f32x16 __attribute__((ext_vector_type(16)));

__device__ __forceinline__ float bcastf(float v, int l) {
    return __int_as_float(__builtin_amdgcn_readlane(__float_as_int(v), l));
}

__device__ __forceinline__ void wave_sum2(float& a, float& b) {
    #pragma unroll
    for (int off = 32; off > 0; off >>= 1) {
        a += __shfl_xor(a, off, 64);
        b += __shfl_xor(b, off, 64);
    }
}

__device__ __forceinline__ short f2bf(float f) {         // RNE
    unsigned u = __float_as_uint(f);
    u = u + 0x7FFFu + ((u >> 16) & 1u);
    return (short)(u >> 16);
}
__device__ __forceinline__ float bf2f(short s) {
    return __uint_as_float(((unsigned)(unsigned short)s) << 16);
}
__device__ __forceinline__ void split_cheap(float f, short& hi, short& lo) {
    unsigned u = __float_as_uint(f);
    unsigned hb = u & 0xffff0000u;
    float lof = f - __uint_as_float(hb);
    hi = (short)(u >> 16);
    lo = (short)(__float_as_uint(lof) >> 16);
}

// pack 8 fp32 -> hi/lo bf16 planes via v_cvt_pk (RNE hi; lo = RNE(v - hi))
__device__ __forceinline__ void pack_plane8(const float* vv, short8& ah, short8& al) {
    union { unsigned u[4]; short8 s; } Uh, Ul;
    #pragma unroll
    for (int i = 0; i < 4; i++) {
        unsigned hw;
        asm("v_cvt_pk_bf16_f32 %0, %1, %2" : "=v"(hw) : "v"(vv[2 * i]), "v"(vv[2 * i + 1]));
        float he = __uint_as_float(hw << 16);
        float ho = __uint_as_float(hw & 0xffff0000u);
        float le = vv[2 * i] - he;
        float lo_ = vv[2 * i + 1] - ho;
        unsigned lw;
        asm("v_cvt_pk_bf16_f32 %0, %1, %2" : "=v"(lw) : "v"(le), "v"(lo_));
        Uh.u[i] = hw; Ul.u[i] = lw;
    }
    ah = Uh.s; al = Ul.s;
}

// pack 16 softmax probs (f32, regs) -> two bf16 B-fragments via cvt_pk + permlane32_swap
__device__ __forceinline__ void pack_pfrag(const float* p, short8& pf0s, short8& pf1s) {
    unsigned w0, w1, w2, w3, u0, u1, u2, u3;
    asm("v_cvt_pk_bf16_f32 %0, %1, %2" : "=v"(w0) : "v"(p[0]), "v"(p[1]));
    asm("v_cvt_pk_bf16_f32 %0, %1, %2" : "=v"(w1) : "v"(p[2]), "v"(p[3]));
    asm("v_cvt_pk_bf16_f32 %0, %1, %2" : "=v"(w2) : "v"(p[4]), "v"(p[5]));
    asm("v_cvt_pk_bf16_f32 %0, %1, %2" : "=v"(w3) : "v"(p[6]), "v"(p[7]));
    asm("v_cvt_pk_bf16_f32 %0, %1, %2" : "=v"(u0) : "v"(p[8]), "v"(p[9]));
    asm("v_cvt_pk_bf16_f32 %0, %1, %2" : "=v"(u1) : "v"(p[10]), "v"(p[11]));
    asm("v_cvt_pk_bf16_f32 %0, %1, %2" : "=v"(u2) : "v"(p[12]), "v"(p[13]));
    asm("v_cvt_pk_bf16_f32 %0, %1, %2" : "=v"(u3) : "v"(p[14]), "v"(p[15]));
    asm("v_permlane32_swap_b32 %0, %1" : "+v"(w0), "+v"(w2));
    asm("v_permlane32_swap_b32 %0, %1" : "+v"(w1), "+v"(w3));
    asm("v_permlane32_swap_b32 %0, %1" : "+v"(u0), "+v"(u2));
    asm("v_permlane32_swap_b32 %0, %1" : "+v"(u1), "+v"(u3));
    union { unsigned u[4]; short8 s; } pf0, pf1;
    pf0.u[0] = w0; pf0.u[1] = w1; pf0.u[2] = w2; pf0.u[3] = w3;
    pf1.u[0] = u0; pf1.u[1] = u1; pf1.u[2] = u2; pf1.u[3] = u3;
    pf0s = pf0.s; pf1s = pf1.s;
}

// --- fused prep: dst histogram+rank, A1 = W1[:, :14] @ xe + b1 (fp32 exact),
//     W2' prepack, b2' fold, w14 pack, ip prepack, vT pad rows (16=ones, 17-31=0) ---
__global__ void hist_prep(const float* __restrict__ x, const float* __restrict__ emb,
                          const int* __restrict__ etype, const int* __restrict__ ei,
                          const float* __restrict__ w1, const float* __restrict__ b1,
                          const float* __restrict__ w2, const float* __restrict__ lng,
                          const float* __restrict__ lnb, const float* __restrict__ b2,
                          const float* __restrict__ ipw,
                          float* __restrict__ A1, int* __restrict__ cnt, int* __restrict__ rank,
                          unsigned short* __restrict__ w2fh, unsigned short* __restrict__ w2fl,
                          unsigned short* __restrict__ ipfh, unsigned short* __restrict__ ipfl,
                          float* __restrict__ b2p, float* __restrict__ w14p,
                          unsigned short* __restrict__ vT) {
    int tid = blockIdx.x * 256 + threadIdx.x;    // grid exactly E
    int d = ei[N_EDGES + tid];
    rank[tid] = atomicAdd(&cnt[d], 1);
    if (tid < N_NODES * 64) {
        int n = tid >> 6, f = tid & 63;
        const float* wr = w1 + f * 15;
        float acc = b1[f];
        #pragma unroll
        for (int k = 0; k < 6; k++) acc = fmaf(x[n * 6 + k], wr[k], acc);
        int e = etype[n];
        #pragma unroll
        for (int k = 0; k < 8; k++) acc = fmaf(emb[e * 8 + k], wr[6 + k], acc);
        A1[tid] = acc;
    }
    if (tid < 262144) {   // vT pad rows: 4 heads x rows 16..31 x 4096 nodes
        int vh = tid >> 16;
        int rem = tid & 65535;
        int dd = rem >> 12;        // 0..15 -> row 16+dd
        int nd = rem & 4095;
        vT[((size_t)(vh * 32 + 16 + dd)) * N_NODES + nd] = (dd == 0) ? 0x3F80 : 0;
    }
    if (tid < 4096) {
        int idx = tid >> 9, ln = (tid >> 3) & 63, j = tid & 7;
        int mm = ln & 15, qq = ln >> 4;
        int g = idx >> 1, tt = idx & 1;
        int col = tt * 32 + qq * 8 + j;
        float w = w2[(g * 16 + mm) * 64 + col] * lng[col];
        short hi = f2bf(w);
        w2fh[tid] = (unsigned short)hi;
        w2fl[tid] = (unsigned short)f2bf(w - bf2f(hi));
    }
    if (tid < 12288) {
        int idx = tid >> 9, ln = (tid >> 3) & 63, j = tid & 7;
        int mm = ln & 15, qq = ln >> 4;
        int og = idx >> 1, tt = idx & 1;
        float w = ipw[(og * 16 + mm) * 64 + tt * 32 + qq * 8 + j];
        short hi = f2bf(w);
        ipfh[tid] = (unsigned short)hi;
        ipfl[tid] = (unsigned short)f2bf(w - bf2f(hi));
    }
    if (tid < 64) {
        float acc = b2[tid];
        for (int c = 0; c < 64; c++) acc = fmaf(w2[tid * 64 + c], lnb[c], acc);
        b2p[tid] = acc;
        w14p[tid] = w1[tid * 15 + 14];
    }
}

// ------- scatter with in-block scan (int4 cnt loads, unchanged) -------
__global__ void __launch_bounds__(256) scatter_scan(
        const int* __restrict__ cnt, const int* __restrict__ ei,
        const float* __restrict__ edge_attr, const int* __restrict__ rank,
        int* __restrict__ bnd,
        int* __restrict__ ssrc, float* __restrict__ sea) {
    __shared__ int lbnd[4096];
    __shared__ int wsum[4];
    int t = threadIdx.x;
    int base = t * 16;
    int v16[16];
    int T = 0;
    #pragma unroll
    for (int j4 = 0; j4 < 4; j4++) {
        int4 c4 = ((const int4*)cnt)[t * 4 + j4];
        v16[j4 * 4 + 0] = c4.x; v16[j4 * 4 + 1] = c4.y;
        v16[j4 * 4 + 2] = c4.z; v16[j4 * 4 + 3] = c4.w;
        T += c4.x + c4.y + c4.z + c4.w;
    }
    int inc = T;
    int l = t & 63;
    #pragma unroll
    for (int off = 1; off < 64; off <<= 1) {
        int v = __shfl_up(inc, off, 64);
        if (l >= off) inc += v;
    }
    if (l == 63) wsum[t >> 6] = inc;
    __syncthreads();
    int wo = 0;
    for (int w = 0; w < (t >> 6); w++) wo += wsum[w];
    int run = wo + inc - T;
    #pragma unroll
    for (int j = 0; j < 16; j++) {
        lbnd[base + j] = run;
        run += v16[j];
    }
    if (blockIdx.x == 0) {
        #pragma unroll
        for (int j = 0; j < 16; j++) bnd[base + j] = lbnd[base + j];
        if (t == 255) bnd[4096] = run;
    }
    __syncthreads();
    int e = blockIdx.x * 256 + t;
    int d = ei[N_EDGES + e];
    int pos = lbnd[d] + rank[e];
    ssrc[pos] = ei[e];
    sea[pos] = edge_attr[e];
}

// ---------------- edge MLP v5: swapped layer-2 MFMA + 2-deep decoupled prefetch (unchanged) ---
__global__ void __launch_bounds__(256, 3) edge_gather_mfma(
        const float* __restrict__ A1,
        const int* __restrict__ ssrc, const float* __restrict__ sea,
        const int* __restrict__ bnd,
        const unsigned short* __restrict__ w2fh, const unsigned short* __restrict__ w2fl,
        const float* __restrict__ w14p, const float* __restrict__ b2p,
        const float* __restrict__ lg, const float* __restrict__ lb,
        float* __restrict__ h) {
    __shared__ uint4 lw2h4[512];
    __shared__ uint4 lw2l4[512];
    int tid = threadIdx.x;
    {   // stage W2' hi/lo fragments (8 KB each) into LDS
        const uint4* gh = (const uint4*)w2fh;
        const uint4* gl = (const uint4*)w2fl;
        lw2h4[tid] = gh[tid];
        lw2h4[tid + 256] = gh[tid + 256];
        lw2l4[tid] = gl[tid];
        lw2l4[tid + 256] = gl[tid + 256];
    }
    const unsigned short* lw2h = (const unsigned short*)lw2h4;
    const unsigned short* lw2l = (const unsigned short*)lw2l4;

    int lane = tid & 63;
    int wv = tid >> 6;
    int m = lane & 15;
    int q = lane >> 4;

    float w14f[16];
    {
        float4 wa = *(const float4*)(w14p + q * 8);
        float4 wb = *(const float4*)(w14p + q * 8 + 4);
        float4 wc = *(const float4*)(w14p + 32 + q * 8);
        float4 wd = *(const float4*)(w14p + 32 + q * 8 + 4);
        w14f[0] = wa.x; w14f[1] = wa.y; w14f[2] = wa.z; w14f[3] = wa.w;
        w14f[4] = wb.x; w14f[5] = wb.y; w14f[6] = wb.z; w14f[7] = wb.w;
        w14f[8] = wc.x; w14f[9] = wc.y; w14f[10] = wc.z; w14f[11] = wc.w;
        w14f[12] = wd.x; w14f[13] = wd.y; w14f[14] = wd.z; w14f[15] = wd.w;
    }
    float b2v[16];
    #pragma unroll
    for (int g = 0; g < 4; g++) {
        float4 bb = *(const float4*)(b2p + g * 16 + q * 4);
        b2v[g * 4 + 0] = bb.x; b2v[g * 4 + 1] = bb.y;
        b2v[g * 4 + 2] = bb.z; b2v[g * 4 + 3] = bb.w;
    }
    __syncthreads();

    int node = blockIdx.x * 4 + wv;
    int start = bnd[node], end = bnd[node + 1];
    int ntiles = (end - start + 15) >> 4;
    float acc[16];
    #pragma unroll
    for (int i = 0; i < 16; i++) acc[i] = 0.f;

    if (ntiles > 0) {
        int ec0 = start + m; if (ec0 >= end) ec0 = end - 1;
        int srcn0 = ssrc[ec0]; float eav0 = sea[ec0];
        int srcn1 = srcn0; float eav1 = eav0;
        if (ntiles > 1) {
            int ec1 = start + 16 + m; if (ec1 >= end) ec1 = end - 1;
            srcn1 = ssrc[ec1]; eav1 = sea[ec1];
        }
        const float* ar = A1 + srcn0 * 64 + q * 8;
        float4 va = *(const float4*)(ar);
        float4 vb = *(const float4*)(ar + 4);
        float4 vc = *(const float4*)(ar + 32);
        float4 vd = *(const float4*)(ar + 36);

        for (int t = 0; t < ntiles; t++) {
            int base = start + t * 16;
            const float* arn = A1 + srcn1 * 64 + q * 8;
            float4 na = *(const float4*)(arn);
            float4 nb = *(const float4*)(arn + 4);
            float4 nc = *(const float4*)(arn + 32);
            float4 nd = *(const float4*)(arn + 36);
            int srcn2 = srcn1; float eav2 = eav1;
            if (t + 2 < ntiles) {
                int ec2 = base + 32 + m; if (ec2 >= end) ec2 = end - 1;
                srcn2 = ssrc[ec2]; eav2 = sea[ec2];
            }
            float v[16] = {va.x, va.y, va.z, va.w, vb.x, vb.y, vb.z, vb.w,
                           vc.x, vc.y, vc.z, vc.w, vd.x, vd.y, vd.z, vd.w};
            float eavc = eav0;
            float s = 0.f, s2 = 0.f;
            #pragma unroll
            for (int j = 0; j < 16; j++) {
                float u = fmaxf(fmaf(w14f[j], eavc, v[j]), 0.f);
                v[j] = u;
                s += u;
                s2 = fmaf(u, u, s2);
            }
            s += __shfl_xor(s, 16, 64);  s2 += __shfl_xor(s2, 16, 64);
            s += __shfl_xor(s, 32, 64);  s2 += __shfl_xor(s2, 32, 64);
            float mean = s * (1.f / 64.f);
            float var = s2 * (1.f / 64.f) - mean * mean;
            float rs = rsqrtf(var + 1e-5f);
            float a0 = -mean * rs;
            #pragma unroll
            for (int j = 0; j < 16; j++) v[j] = fmaf(v[j], rs, a0);
            short8 a2h[2], a2l[2];
            pack_plane8(v, a2h[0], a2l[0]);
            pack_plane8(v + 8, a2h[1], a2l[1]);
            int ob = (t >> 20);
            float s_ = 0.f, s2_ = 0.f;
            float t2v[16];
            #pragma unroll
            for (int g = 0; g < 4; g++) {
                f32x4 c = {0.f, 0.f, 0.f, 0.f};
                #pragma unroll
                for (int t2 = 0; t2 < 2; t2++) {
                    short8 bh = *(const short8*)(lw2h + ((g * 2 + t2) * 64 + lane + ob) * 8);
                    short8 bl = *(const short8*)(lw2l + ((g * 2 + t2) * 64 + lane + ob) * 8);
                    c = __builtin_amdgcn_mfma_f32_16x16x32_bf16(bh, a2l[t2], c, 0, 0, 0);
                    c = __builtin_amdgcn_mfma_f32_16x16x32_bf16(bl, a2h[t2], c, 0, 0, 0);
                    c = __builtin_amdgcn_mfma_f32_16x16x32_bf16(bh, a2h[t2], c, 0, 0, 0);
                }
                #pragma unroll
                for (int r = 0; r < 4; r++) {
                    float vv = fmaxf(c[r] + b2v[g * 4 + r], 0.f);
                    t2v[g * 4 + r] = vv;
                    s_ += vv;
                    s2_ = fmaf(vv, vv, s2_);
                }
            }
            s_ += __shfl_xor(s_, 16, 64);  s2_ += __shfl_xor(s2_, 16, 64);
            s_ += __shfl_xor(s_, 32, 64);  s2_ += __shfl_xor(s2_, 32, 64);
            float mean2 = s_ * (1.f / 64.f);
            float var2 = s2_ * (1.f / 64.f) - mean2 * mean2;
            float rs2 = rsqrtf(var2 + 1e-5f);
            float a02 = -mean2 * rs2;
            if (base + m < end) {
                #pragma unroll
                for (int i = 0; i < 16; i++) acc[i] += fmaf(t2v[i], rs2, a02);
            }
            va = na; vb = nb; vc = nc; vd = nd;
            eav0 = eav1; eav1 = eav2; srcn1 = srcn2;
        }
    }
    #pragma unroll
    for (int off = 1; off < 16; off <<= 1)
        #pragma unroll
        for (int i = 0; i < 16; i++) acc[i] += __shfl_xor(acc[i], off, 64);
    if (m == 0) {
        float deg = (float)(end - start);
        #pragma unroll
        for (int g = 0; g < 4; g++) {
            float4 lgv = *(const float4*)(lg + g * 16 + q * 4);
            float4 lbv = *(const float4*)(lb + g * 16 + q * 4);
            float* hp = h + node * 64 + g * 16 + q * 4;
            hp[0] = lgv.x * acc[g * 4 + 0] + deg * lbv.x;
            hp[1] = lgv.y * acc[g * 4 + 1] + deg * lbv.y;
            hp[2] = lgv.z * acc[g * 4 + 2] + deg * lbv.z;
            hp[3] = lgv.w * acc[g * 4 + 3] + deg * lbv.w;
        }
    }
}

// ------- qkv via MFMA: 3072 wave-tasks, 768 blocks (vT 32-row layout) -------
__global__ void __launch_bounds__(256) qkv_mfma(
        const float* __restrict__ h, const float* __restrict__ b,
        const unsigned short* __restrict__ ipfh, const unsigned short* __restrict__ ipfl,
        unsigned short* __restrict__ qhp, unsigned short* __restrict__ qlp,
        unsigned short* __restrict__ khp, unsigned short* __restrict__ klp,
        unsigned short* __restrict__ vT) {
    int lane = threadIdx.x & 63;
    int wv = threadIdx.x >> 6;
    int m = lane & 15;
    int q = lane >> 4;
    int wid = blockIdx.x * 4 + wv;   // 0..3071
    int tile = wid / 12;
    int og = wid - tile * 12;
    short8 bh[2], bl[2];
    #pragma unroll
    for (int t = 0; t < 2; t++) {
        bh[t] = *(const short8*)(ipfh + ((og * 2 + t) * 64 + lane) * 8);
        bl[t] = *(const short8*)(ipfl + ((og * 2 + t) * 64 + lane) * 8);
    }
    f32x4 c = {0.f, 0.f, 0.f, 0.f};
    #pragma unroll
    for (int t = 0; t < 2; t++) {
        const float* hr = h + (tile * 16 + m) * 64 + t * 32 + q * 8;
        float4 f0 = *(const float4*)hr;
        float4 f1 = *(const float4*)(hr + 4);
        float av8[8] = {f0.x, f0.y, f0.z, f0.w, f1.x, f1.y, f1.z, f1.w};
        short8 ah, al;
        #pragma unroll
        for (int j = 0; j < 8; j++) {
            short hi, lo;
            split_cheap(av8[j], hi, lo);
            ah[j] = hi;
            al[j] = lo;
        }
        c = __builtin_amdgcn_mfma_f32_16x16x32_bf16(al, bh[t], c, 0, 0, 0);
        c = __builtin_amdgcn_mfma_f32_16x16x32_bf16(ah, bl[t], c, 0, 0, 0);
        c = __builtin_amdgcn_mfma_f32_16x16x32_bf16(ah, bh[t], c, 0, 0, 0);
    }
    int o = og * 16 + m;
    float bias = b[o];
    #pragma unroll
    for (int r = 0; r < 4; r++) {
        int node = tile * 16 + q * 4 + r;   // C-layout row = (lane>>4)*4 + reg
        float val = c[r] + bias;
        if (og < 4) {
            float aq = val * (0.25f * 1.44269504f);   // fold 1/sqrt(16)*log2(e)
            size_t idx = ((size_t)(og * N_NODES + node)) * 16 + m;
            short hi = f2bf(aq);
            qhp[idx] = (unsigned short)hi;
            qlp[idx] = (unsigned short)f2bf(aq - bf2f(hi));
        } else if (og < 8) {
            size_t idx = ((size_t)((og - 4) * N_NODES + node)) * 16 + m;
            short hi = f2bf(val);
            khp[idx] = (unsigned short)hi;
            klp[idx] = (unsigned short)f2bf(val - bf2f(hi));
        } else {
            // vT 32-row layout: head = og-8, row = m (feat d), rows 16..31 pre-filled
            vT[((size_t)((og - 8) * 32 + m)) * N_NODES + node] = (unsigned short)f2bf(val);
        }
    }
}

// ------- attention v4: dual S-tiles + restored K prefetch + padded-vT unconditional V loads,
//         __launch_bounds__(256,4) caps VGPR at 128 (4 waves/SIMD) ----------
__global__ void __launch_bounds__(256, 4) attn_mfma(
        const unsigned short* __restrict__ qhp, const unsigned short* __restrict__ qlp,
        const unsigned short* __restrict__ khp, const unsigned short* __restrict__ klp,
        const unsigned short* __restrict__ vT,
        float* __restrict__ part_o, float* __restrict__ part_ml) {
    int lane = threadIdx.x & 63;
    int wv = threadIdx.x >> 6;
    int l31 = lane & 31;
    int hi = lane >> 5;

    int wid = blockIdx.x * 4 + wv;     // 0..4095
    int kc = wid & 7;                  // 8 chunks of 512 keys
    int wqt = (wid >> 3) & 127;        // 128 tiles of 32 q-rows
    int head = wid >> 10;

    int qrow = wqt * 32 + l31;
    short8 aqh = *(const short8*)(qhp + ((size_t)(head * N_NODES + qrow)) * 16 + hi * 8);
    short8 aql = *(const short8*)(qlp + ((size_t)(head * N_NODES + qrow)) * 16 + hi * 8);

    const unsigned short* khb = khp + (size_t)head * N_NODES * 16;
    const unsigned short* klb = klp + (size_t)head * N_NODES * 16;
    const unsigned short* vtb = vT + (size_t)(head * 32 + l31) * N_NODES;  // row = l31 (16=ones, 17+=0)

    float mS = -3e38f;
    f32x16 Ot = {0.f, 0.f, 0.f, 0.f, 0.f, 0.f, 0.f, 0.f,
                 0.f, 0.f, 0.f, 0.f, 0.f, 0.f, 0.f, 0.f};

    size_t k0 = ((size_t)(kc * 512 + l31)) * 16 + hi * 8;
    short8 kah = *(const short8*)(khb + k0);
    short8 kal = *(const short8*)(klb + k0);
    short8 kbh = *(const short8*)(khb + k0 + 512);
    short8 kbl = *(const short8*)(klb + k0 + 512);

    for (int it = 0; it < 8; it++) {
        int n0 = kc * 512 + it * 64;
        // prefetch next iteration's K fragments (clamped; redundant reload on last iter)
        int itn = (it + 1 < 8) ? (it + 1) : 7;
        size_t kn = ((size_t)(kc * 512 + itn * 64 + l31)) * 16 + hi * 8;
        short8 nkah = *(const short8*)(khb + kn);
        short8 nkal = *(const short8*)(klb + kn);
        short8 nkbh = *(const short8*)(khb + kn + 512);
        short8 nkbl = *(const short8*)(klb + kn + 512);
        // V loads for this iteration (unconditional, padded layout) — hide under QK+softmax
        short8 v0a = *(const short8*)(vtb + n0 + hi * 8);
        short8 v1a = *(const short8*)(vtb + n0 + 16 + hi * 8);
        short8 v0b = *(const short8*)(vtb + n0 + 32 + hi * 8);
        short8 v1b = *(const short8*)(vtb + n0 + 48 + hi * 8);
        // two independent 32-key S-tiles: 6 interleavable MFMAs
        f32x16 SA = {0.f, 0.f, 0.f, 0.f, 0.f, 0.f, 0.f, 0.f,
                     0.f, 0.f, 0.f, 0.f, 0.f, 0.f, 0.f, 0.f};
        f32x16 SB = SA;
        SA = __builtin_amdgcn_mfma_f32_32x32x16_bf16(kah, aql, SA, 0, 0, 0);
        SB = __builtin_amdgcn_mfma_f32_32x32x16_bf16(kbh, aql, SB, 0, 0, 0);
        SA = __builtin_amdgcn_mfma_f32_32x32x16_bf16(kal, aqh, SA, 0, 0, 0);
        SB = __builtin_amdgcn_mfma_f32_32x32x16_bf16(kbl, aqh, SB, 0, 0, 0);
        SA = __builtin_amdgcn_mfma_f32_32x32x16_bf16(kah, aqh, SA, 0, 0, 0);
        SB = __builtin_amdgcn_mfma_f32_32x32x16_bf16(kbh, aqh, SB, 0, 0, 0);
        // per-q max over 64 keys: depth-5 tree + partner-half swap
        float t0[8];
        #pragma unroll
        for (int r = 0; r < 8; r++)
            t0[r] = fmaxf(fmaxf(SA[r], SA[r + 8]), fmaxf(SB[r], SB[r + 8]));
        t0[0] = fmaxf(t0[0], t0[4]); t0[1] = fmaxf(t0[1], t0[5]);
        t0[2] = fmaxf(t0[2], t0[6]); t0[3] = fmaxf(t0[3], t0[7]);
        t0[0] = fmaxf(t0[0], t0[2]); t0[1] = fmaxf(t0[1], t0[3]);
        float mr = fmaxf(t0[0], t0[1]);
        mr = fmaxf(mr, __shfl_xor(mr, 32, 64));
        if (!__all(mr <= mS)) {          // exact skip: alpha == 1 when no new max
            float mn = fmaxf(mS, mr);
            float alpha = exp2f(mS - mn);
            mS = mn;
            #pragma unroll
            for (int r = 0; r < 9; r++) Ot[r] *= alpha;   // regs 0..7 = O, reg 8 = l
        }
        // softmax in place, both tiles
        #pragma unroll
        for (int r = 0; r < 16; r++) SA[r] = exp2f(SA[r] - mS);
        #pragma unroll
        for (int r = 0; r < 16; r++) SB[r] = exp2f(SB[r] - mS);
        // sub-tile A: pack + PV
        {
            float p[16];
            #pragma unroll
            for (int r = 0; r < 16; r++) p[r] = SA[r];
            short8 pf0, pf1;
            pack_pfrag(p, pf0, pf1);
            Ot = __builtin_amdgcn_mfma_f32_32x32x16_bf16(v0a, pf0, Ot, 0, 0, 0);
            Ot = __builtin_amdgcn_mfma_f32_32x32x16_bf16(v1a, pf1, Ot, 0, 0, 0);
        }
        // sub-tile B: pack + PV
        {
            float p[16];
            #pragma unroll
            for (int r = 0; r < 16; r++) p[r] = SB[r];
            short8 pf0, pf1;
            pack_pfrag(p, pf0, pf1);
            Ot = __builtin_amdgcn_mfma_f32_32x32x16_bf16(v0b, pf0, Ot, 0, 0, 0);
            Ot = __builtin_amdgcn_mfma_f32_32x32x16_bf16(v1b, pf1, Ot, 0, 0, 0);
        }
        kah = nkah; kal = nkal; kbh = nkbh; kbl = nkbl;
    }
    int qt16 = wqt * 2 + (l31 >> 4);
    int qi = l31 & 15;
    size_t pb = ((size_t)(head * 8 + kc) * 256 + qt16) * 256;
    f32x4 o0 = {Ot[0], Ot[1], Ot[2], Ot[3]};
    f32x4 o1 = {Ot[4], Ot[5], Ot[6], Ot[7]};
    *(f32x4*)(part_o + pb + qi * 16 + hi * 4) = o0;
    *(f32x4*)(part_o + pb + qi * 16 + 8 + hi * 4) = o1;
    if (lane < 32) {
        size_t mb = ((size_t)(head * 8 + kc) * 256 + qt16) * 32;
        part_ml[mb + qi] = mS;
        part_ml[mb + 16 + qi] = Ot[8];
    }
}

// ---------------- fused merge (8 chunks) + out_proj + residual + LN + final (unchanged) ------
__global__ void post_kernel(const float* __restrict__ h,
                            const float* __restrict__ part_o, const float* __restrict__ part_ml,
                            const float* __restrict__ opw, const float* __restrict__ opb,
                            const float* __restrict__ ag, const float* __restrict__ ab,
                            const float* __restrict__ ow, const float* __restrict__ ob,
                            float* __restrict__ out) {
    __shared__ float wl1[64 * 65];
    __shared__ float wl2[64 * 65];
    for (int i = threadIdx.x; i < 4096; i += blockDim.x) {
        int r = i >> 6, c = i & 63;
        wl1[r * 65 + c] = opw[i];
        wl2[r * 65 + c] = ow[i];
    }
    __syncthreads();
    int lane = threadIdx.x & 63;
    int n = blockIdx.x * 4 + (threadIdx.x >> 6);
    int j = lane;
    int head = j >> 4, d = j & 15;
    int qt = n >> 4, qi = n & 15;
    float M = -3e38f, L = 0.f, Ov = 0.f;
    #pragma unroll
    for (int c = 0; c < 8; c++) {
        size_t base = ((size_t)(head * 8 + c) * 256 + qt);
        float mc = part_ml[base * 32 + qi];
        float lc = part_ml[base * 32 + 16 + qi];
        float ov = part_o[base * 256 + qi * 16 + d];
        if (mc > M) {
            float sc = exp2f(M - mc);
            M = mc;
            L = L * sc + lc;
            Ov = Ov * sc + ov;
        } else {
            float sc = exp2f(mc - M);
            L = fmaf(lc, sc, L);
            Ov = fmaf(ov, sc, Ov);
        }
    }
    float oj = Ov / L;
    float acc = opb[j];
    #pragma unroll
    for (int k = 0; k < 64; k++) acc = fmaf(wl1[j * 65 + k], bcastf(oj, k), acc);
    float r = h[n * 64 + j] + acc;
    float s = r, s2 = r * r;
    wave_sum2(s, s2);
    float mean = s * (1.f / 64.f);
    float var = s2 * (1.f / 64.f) - mean * mean;
    float hn = (r - mean) * rsqrtf(var + 1e-5f) * ag[j] + ab[j];
    float acc2 = ob[j];
    #pragma unroll
    for (int k = 0; k < 64; k++) acc2 = fmaf(wl2[j * 65 + k], bcastf(hn, k), acc2);
    out[n * 64 + j] = acc2;
}

extern "C" void kernel_launch(void* const* d_in, const int* in_sizes, int n_in,
                              void* d_out, int out_size, void* d_ws, size_t ws_size,
                              hipStream_t stream) {
    const float* x        = (const float*)d_in[0];
    const float* edge_attr= (const float*)d_in[1];
    const float* emb      = (const float*)d_in[2];
    const float* lin1_w   = (const float*)d_in[3];
    const float* lin1_b   = (const float*)d_in[4];
    const float* lay_w    = (const float*)d_in[5];
    const float* lay_b    = (const float*)d_in[6];
    const float* ln_g     = (const float*)d_in[7];
    const float* ln_b     = (const float*)d_in[8];
    const float* ipw      = (const float*)d_in[9];
    const float* ipb      = (const float*)d_in[10];
    const float* opw      = (const float*)d_in[11];
    const float* opb      = (const float*)d_in[12];
    const float* ang      = (const float*)d_in[13];
    const float* anb      = (const float*)d_in[14];
    const float* ow       = (const float*)d_in[15];
    const float* ob       = (const float*)d_in[16];
    const int*   ei       = (const int*)d_in[17];
    const int*   et       = (const int*)d_in[18];

    char* wsb = (char*)d_ws;
    size_t off = 0;
    float* A1             = (float*)(wsb + off);          off += 1048576;
    float* h              = (float*)(wsb + off);          off += 1048576;
    unsigned short* qhp   = (unsigned short*)(wsb + off); off += 524288;
    unsigned short* qlp   = (unsigned short*)(wsb + off); off += 524288;
    unsigned short* khp   = (unsigned short*)(wsb + off); off += 524288;
    unsigned short* klp   = (unsigned short*)(wsb + off); off += 524288;
    unsigned short* vT    = (unsigned short*)(wsb + off); off += 1048576;   // 4 heads x 32 rows x 4096
    float* part_o         = (float*)(wsb + off);          off += 8388608;
    float* part_ml        = (float*)(wsb + off);          off += 1048576;
    int*   cnt            = (int*)(wsb + off);            off += 16384;
    int*   bnd            = (int*)(wsb + off);            off += 16388;
    off = (off + 255) & ~(size_t)255;
    int*   rank           = (int*)(wsb + off);            off += 2097152;
    int*   ssrc           = (int*)(wsb + off);            off += 2097152;
    float* sea            = (float*)(wsb + off);          off += 2097152;
    unsigned short* w2fh  = (unsigned short*)(wsb + off); off += 8192;
    unsigned short* w2fl  = (unsigned short*)(wsb + off); off += 8192;
    unsigned short* ipfh  = (unsigned short*)(wsb + off); off += 24576;
    unsigned short* ipfl  = (unsigned short*)(wsb + off); off += 24576;
    float* b2p            = (float*)(wsb + off);          off += 256;
    float* w14p           = (float*)(wsb + off);          off += 256;

    (void)hipMemsetAsync(cnt, 0, 4096 * sizeof(int), stream);
    hist_prep<<<2048, 256, 0, stream>>>(x, emb, et, ei, lin1_w, lin1_b, lay_w, ln_g, ln_b,
                                        lay_b, ipw, A1, cnt, rank, w2fh, w2fl, ipfh, ipfl,
                                        b2p, w14p, vT);
    scatter_scan<<<2048, 256, 0, stream>>>(cnt, ei, edge_attr, rank, bnd, ssrc, sea);
    edge_gather_mfma<<<1024, 256, 0, stream>>>(A1, ssrc, sea, bnd, w2fh, w2fl,
                                               w14p, b2p, ln_g, ln_b, h);
    qkv_mfma<<<768, 256, 0, stream>>>(h, ipb, ipfh, ipfl, qhp, qlp, khp, klp, vT);
    attn_mfma<<<1024, 256, 0, stream>>>(qhp, qlp, khp, klp, vT, part_o, part_ml);
    post_kernel<<<1024, 256, 0, stream>>>(h, part_o, part_ml, opw, opb, ang, anb, ow, ob,
                                          (float*)d_out);
}